// Round 17
// baseline (247.418 us; speedup 1.0000x reference)
//
#include <hip/hip_runtime.h>
#include <hip/hip_bf16.h>

#define NN   4096
#define EE   262144
#define ET   (EE + NN)
#define HH   4
#define EMB  256
#define DFF  128
#define FIN  128
#define KSPLIT 8
#define KCHUNK (NN / KSPLIT)

typedef float  f32x16  __attribute__((ext_vector_type(16)));
typedef __bf16 bf16x8  __attribute__((ext_vector_type(8)));
typedef unsigned short u16;
typedef unsigned short u16x4 __attribute__((ext_vector_type(4)));

__device__ __forceinline__ u16 f2bf(float f) {
  unsigned u = __float_as_uint(f);
  u += 0x7fffu + ((u >> 16) & 1u);   // RNE
  return (u16)(u >> 16);
}
// hi/lo bf16 split packed into one uint: lo16 = hi-part, hi16 = lo-part
__device__ __forceinline__ unsigned split1(float x) {
  const u16 h = f2bf(x);
  const float hf = __uint_as_float(((unsigned)h) << 16);
  const u16 l = f2bf(x - hf);
  return (unsigned)h | ((unsigned)l << 16);
}

// ------- split-precision MFMA GEMM, B in [K,Nn] layout (xh = tgt @ W_gat) -------
__global__ __launch_bounds__(256) void mgemm_nt(
    const float* __restrict__ A, const float* __restrict__ B,
    float* __restrict__ Cf, int M, int Nn, int K)
{
  __shared__ u16 Ah[64][40], Al[64][40], Bh[64][40], Bl[64][40];
  const int tid = threadIdx.x;
  const int m0 = blockIdx.y * 64, n0 = blockIdx.x * 64;
  const int w = tid >> 6, l = tid & 63, lq = l & 31, hi = l >> 5;
  const int wm = w >> 1, wn = w & 1;
  f32x16 acc = {0};
  for (int k0 = 0; k0 < K; k0 += 32) {
    __syncthreads();
#pragma unroll
    for (int it = 0; it < 2; ++it) {
      const int idx = tid + it * 256;
      {  // A[M,K]: row-major
        const int row = idx >> 3, slot = idx & 7;
        const float4 av = *(const float4*)(A + (size_t)(m0 + row) * K + k0 + slot * 4);
        const unsigned s0 = split1(av.x), s1 = split1(av.y), s2 = split1(av.z), s3 = split1(av.w);
        u16x4 hp = {(u16)s0, (u16)s1, (u16)s2, (u16)s3};
        u16x4 lp = {(u16)(s0 >> 16), (u16)(s1 >> 16), (u16)(s2 >> 16), (u16)(s3 >> 16)};
        *(u16x4*)(&Ah[row][slot * 4]) = hp;
        *(u16x4*)(&Al[row][slot * 4]) = lp;
      }
      {  // B[K,Nn]: stage transposed -> Bh[col][k]
        const int kr = idx >> 4, nq = idx & 15;
        const float4 bv = *(const float4*)(B + (size_t)(k0 + kr) * Nn + n0 + nq * 4);
        const unsigned s0 = split1(bv.x), s1 = split1(bv.y), s2 = split1(bv.z), s3 = split1(bv.w);
        Bh[nq * 4 + 0][kr] = (u16)s0; Bl[nq * 4 + 0][kr] = (u16)(s0 >> 16);
        Bh[nq * 4 + 1][kr] = (u16)s1; Bl[nq * 4 + 1][kr] = (u16)(s1 >> 16);
        Bh[nq * 4 + 2][kr] = (u16)s2; Bl[nq * 4 + 2][kr] = (u16)(s2 >> 16);
        Bh[nq * 4 + 3][kr] = (u16)s3; Bl[nq * 4 + 3][kr] = (u16)(s3 >> 16);
      }
    }
    __syncthreads();
#pragma unroll
    for (int c = 0; c < 2; ++c) {
      const bf16x8 ah = *(const bf16x8*)(&Ah[wm * 32 + lq][c * 16 + hi * 8]);
      const bf16x8 al = *(const bf16x8*)(&Al[wm * 32 + lq][c * 16 + hi * 8]);
      const bf16x8 bh = *(const bf16x8*)(&Bh[wn * 32 + lq][c * 16 + hi * 8]);
      const bf16x8 bl = *(const bf16x8*)(&Bl[wn * 32 + lq][c * 16 + hi * 8]);
      acc = __builtin_amdgcn_mfma_f32_32x32x16_bf16(ah, bh, acc, 0, 0, 0);
      acc = __builtin_amdgcn_mfma_f32_32x32x16_bf16(ah, bl, acc, 0, 0, 0);
      acc = __builtin_amdgcn_mfma_f32_32x32x16_bf16(al, bh, acc, 0, 0, 0);
    }
  }
  const int col = n0 + wn * 32 + lq;
#pragma unroll
  for (int r = 0; r < 16; ++r) {
    const int row = m0 + wm * 32 + (r & 3) + 8 * (r >> 2) + 4 * hi;
    Cf[(size_t)row * Nn + col] = acc[r];
  }
}

// ------- bf16 MFMA GEMM (out_proj, lin1): C = act(A[M,K] @ B[Nn,K]^T + bias) -------
__global__ __launch_bounds__(256) void bgemm(
    const float* __restrict__ A, const float* __restrict__ B, const float* __restrict__ bias,
    float* __restrict__ Cf, int M, int Nn, int K, int act)
{
  __shared__ u16 As[64][40], Bs[64][40];
  const int tid = threadIdx.x;
  const int m0 = blockIdx.y * 64, n0 = blockIdx.x * 64;
  const int w = tid >> 6, l = tid & 63, lq = l & 31, hi = l >> 5;
  const int wm = w >> 1, wn = w & 1;
  f32x16 acc = {0};
  for (int k0 = 0; k0 < K; k0 += 32) {
    __syncthreads();
#pragma unroll
    for (int it = 0; it < 2; ++it) {
      const int idx = tid + it * 256;
      const int row = idx >> 3, slot = idx & 7;
      const float4 av = *(const float4*)(A + (size_t)(m0 + row) * K + k0 + slot * 4);
      u16x4 ap = {f2bf(av.x), f2bf(av.y), f2bf(av.z), f2bf(av.w)};
      *(u16x4*)(&As[row][slot * 4]) = ap;
      const float4 bv = *(const float4*)(B + (size_t)(n0 + row) * K + k0 + slot * 4);
      u16x4 bp = {f2bf(bv.x), f2bf(bv.y), f2bf(bv.z), f2bf(bv.w)};
      *(u16x4*)(&Bs[row][slot * 4]) = bp;
    }
    __syncthreads();
#pragma unroll
    for (int c = 0; c < 2; ++c) {
      const bf16x8 af = *(const bf16x8*)(&As[wm * 32 + lq][c * 16 + hi * 8]);
      const bf16x8 bf = *(const bf16x8*)(&Bs[wn * 32 + lq][c * 16 + hi * 8]);
      acc = __builtin_amdgcn_mfma_f32_32x32x16_bf16(af, bf, acc, 0, 0, 0);
    }
  }
  const int col = n0 + wn * 32 + lq;
  const float bcol = bias ? bias[col] : 0.f;
#pragma unroll
  for (int r = 0; r < 16; ++r) {
    const int row = m0 + wm * 32 + (r & 3) + 8 * (r >> 2) + 4 * hi;
    float v = acc[r] + bcol;
    if (act == 2) v = fmaxf(v, 0.f);
    Cf[(size_t)row * Nn + col] = v;
  }
}

// ------- fused QKV projection: single bf16 MFMA (outputs bf16-rounded anyway) -------
__global__ __launch_bounds__(256) void qkv_mfma(
    const float* __restrict__ tbuf, const float* __restrict__ mem, const float* __restrict__ orig,
    const float* __restrict__ ipw, const float* __restrict__ ipb,
    u16* __restrict__ qb, u16* __restrict__ kbuf, u16* __restrict__ vT)
{
  __shared__ u16 As[64][40], Bs[64][40];
  const int z = blockIdx.z;
  const float* A = (z == 0) ? tbuf : (z == 1 ? mem : orig);
  const float* B = ipw + (size_t)z * EMB * EMB;
  const float* bias = ipb + z * EMB;
  const float oscale = (z == 0) ? 0.125f : 1.f;
  const int tid = threadIdx.x;
  const int m0 = blockIdx.y * 64, n0 = blockIdx.x * 64;
  const int w = tid >> 6, l = tid & 63, lq = l & 31, hi = l >> 5;
  const int wm = w >> 1, wn = w & 1;
  f32x16 acc = {0};
  for (int k0 = 0; k0 < EMB; k0 += 32) {
    __syncthreads();
#pragma unroll
    for (int it = 0; it < 2; ++it) {
      const int idx = tid + it * 256;
      const int row = idx >> 3, slot = idx & 7;
      const float4 av = *(const float4*)(A + (size_t)(m0 + row) * EMB + k0 + slot * 4);
      u16x4 ap = {f2bf(av.x), f2bf(av.y), f2bf(av.z), f2bf(av.w)};
      *(u16x4*)(&As[row][slot * 4]) = ap;
      const float4 bv = *(const float4*)(B + (size_t)(n0 + row) * EMB + k0 + slot * 4);
      u16x4 bp = {f2bf(bv.x), f2bf(bv.y), f2bf(bv.z), f2bf(bv.w)};
      *(u16x4*)(&Bs[row][slot * 4]) = bp;
    }
    __syncthreads();
#pragma unroll
    for (int c = 0; c < 2; ++c) {
      const bf16x8 af = *(const bf16x8*)(&As[wm * 32 + lq][c * 16 + hi * 8]);
      const bf16x8 bf = *(const bf16x8*)(&Bs[wn * 32 + lq][c * 16 + hi * 8]);
      acc = __builtin_amdgcn_mfma_f32_32x32x16_bf16(af, bf, acc, 0, 0, 0);
    }
  }
  const int col = n0 + wn * 32 + lq;
  const float bcol = bias[col];
  const int hh = col >> 6, dd = col & 63;
#pragma unroll
  for (int r = 0; r < 16; ++r) {
    const int row = m0 + wm * 32 + (r & 3) + 8 * (r >> 2) + 4 * hi;
    const u16 bw = f2bf((acc[r] + bcol) * oscale);
    if (z == 2) vT[((size_t)hh * 64 + dd) * NN + row] = bw;                  // V^T per head
    else if (z == 1) kbuf[((size_t)hh * NN + row) * 64 + dd] = bw;           // K row-major per head
    else qb[((size_t)hh * NN + row) * 64 + dd] = bw;                         // Q (pre-scaled 1/8)
  }
}

// ---------------- a_s / a_d per (node, head) ----------------
__global__ __launch_bounds__(256) void att_sums(const float* __restrict__ xh,
                                                const float* __restrict__ att_src,
                                                const float* __restrict__ att_dst,
                                                float* __restrict__ a_s, float* __restrict__ a_d)
{
  const int n = blockIdx.x, t = threadIdx.x;
  const int h = t >> 6, c = t & 63;
  const float v = xh[(size_t)n * EMB + t];
  float s1 = v * att_src[t];
  float s2 = v * att_dst[t];
#pragma unroll
  for (int off = 32; off >= 1; off >>= 1) {
    s1 += __shfl_down(s1, off);
    s2 += __shfl_down(s2, off);
  }
  if (c == 0) { a_s[n * HH + h] = s1; a_d[n * HH + h] = s2; }
}

// ---------------- counting sort of edges by destination ----------------
__global__ void edge_count(const int* __restrict__ ei, int* __restrict__ counts) {
  const int e = blockIdx.x * blockDim.x + threadIdx.x;
  if (e >= ET) return;
  const int dst = (e < EE) ? ei[EE + e] : (e - EE);
  atomicAdd(&counts[dst], 1);
}

__global__ __launch_bounds__(64) void scan4096(const int* __restrict__ counts, int* __restrict__ offs) {
  const int t = threadIdx.x;
  const int base = t * 64;
  int s = 0;
  for (int i = 0; i < 64; ++i) s += counts[base + i];
  int incl = s;
#pragma unroll
  for (int off = 1; off < 64; off <<= 1) {
    const int v = __shfl_up(incl, off);
    if (t >= off) incl += v;
  }
  int run = incl - s;
  for (int i = 0; i < 64; ++i) { offs[base + i] = run; run += counts[base + i]; }
}

// scatter bumps offs directly (no cursor buffer); offs[dst] ends at segment END.
__global__ void edge_scatter(const int* __restrict__ ei, int* __restrict__ offs,
                             int* __restrict__ ssrc) {
  const int e = blockIdx.x * blockDim.x + threadIdx.x;
  if (e >= ET) return;
  int src, dst;
  if (e < EE) { src = ei[e]; dst = ei[EE + e]; } else { src = dst = e - EE; }
  const int pos = atomicAdd(&offs[dst], 1);
  ssrc[pos] = src;
}

// ---------------- GAT gather: 4-way ILP unroll; beg = offs_end - deg ----------------
__global__ __launch_bounds__(256) void gat_gather(
    const float* __restrict__ xh, const float* __restrict__ a_s, const float* __restrict__ a_d,
    const int* __restrict__ offs, const int* __restrict__ counts, const int* __restrict__ ssrc,
    const float* __restrict__ b_gat, float* __restrict__ t_out)
{
  const int dst = blockIdx.x, tid = threadIdx.x;
  const int h = tid >> 6, c = tid & 63;
  const float ad = a_d[dst * HH + h];
  const int deg = counts[dst];
  const int beg = offs[dst] - deg;           // offs holds segment end after scatter
  float ac0 = 0.f, ac1 = 0.f, ac2 = 0.f, ac3 = 0.f;
  float dn0 = 0.f, dn1 = 0.f, dn2 = 0.f, dn3 = 0.f;
  int i = 0;
  for (; i + 4 <= deg; i += 4) {
    const int s0 = ssrc[beg + i];
    const int s1 = ssrc[beg + i + 1];
    const int s2 = ssrc[beg + i + 2];
    const int s3 = ssrc[beg + i + 3];
    const float A0 = a_s[s0 * HH + h];
    const float A1 = a_s[s1 * HH + h];
    const float A2 = a_s[s2 * HH + h];
    const float A3 = a_s[s3 * HH + h];
    const float x0 = xh[(size_t)s0 * EMB + h * 64 + c];
    const float x1 = xh[(size_t)s1 * EMB + h * 64 + c];
    const float x2 = xh[(size_t)s2 * EMB + h * 64 + c];
    const float x3 = xh[(size_t)s3 * EMB + h * 64 + c];
    float a0 = A0 + ad; a0 = a0 > 0.f ? a0 : 0.2f * a0;
    float a1 = A1 + ad; a1 = a1 > 0.f ? a1 : 0.2f * a1;
    float a2 = A2 + ad; a2 = a2 > 0.f ? a2 : 0.2f * a2;
    float a3 = A3 + ad; a3 = a3 > 0.f ? a3 : 0.2f * a3;
    const float p0 = __expf(a0);
    const float p1 = __expf(a1);
    const float p2 = __expf(a2);
    const float p3 = __expf(a3);
    dn0 += p0; ac0 += p0 * x0;
    dn1 += p1; ac1 += p1 * x1;
    dn2 += p2; ac2 += p2 * x2;
    dn3 += p3; ac3 += p3 * x3;
  }
  for (; i < deg; ++i) {
    const int src = ssrc[beg + i];
    float a = a_s[src * HH + h] + ad;
    a = a > 0.f ? a : 0.2f * a;
    const float p = __expf(a);
    dn0 += p;
    ac0 += p * xh[(size_t)src * EMB + h * 64 + c];
  }
  const float den = (dn0 + dn1) + (dn2 + dn3);
  const float accv = (ac0 + ac1) + (ac2 + ac3);
  float v = accv / (den + 1e-16f) + b_gat[tid];
  v = v > 0.f ? v : 0.01f * v;
  t_out[(size_t)dst * EMB + tid] = v;
}

// ---------------- flash attention: exact R11/R14/R15 body (VGPR=64, occ ~40%) — FROZEN ----------------
// __launch_bounds__(256,8) pins the allocator at the 64-VGPR bucket (insurance; no-op at 64).
// po layout: po[(h*NN + q) * (KSPLIT*64) + i*64 + d]  -> combine2 reads contiguous.
__global__ __launch_bounds__(256, 8) void flash32(
    const u16* __restrict__ qb, const u16* __restrict__ kb,
    const u16* __restrict__ vT, float* __restrict__ po,
    float* __restrict__ pm, float* __restrict__ pl)
{
  __shared__ float sld[4][32 * 33];            // per-wave transpose staging (17 KB)
  const int h = blockIdx.y;
  const int qgroup = blockIdx.x / KSPLIT, ks = blockIdx.x % KSPLIT;
  const int w = threadIdx.x >> 6, l = threadIdx.x & 63;
  const int lq = l & 31, hi = l >> 5;
  const int qtile = qgroup * 4 + w;            // 4 waves share the K/V stream (L1 reuse)
  const int q0 = qtile * 32;
  const u16* qh = qb + (size_t)h * NN * 64;
  const u16* kh = kb + (size_t)h * NN * 64;
  const u16* vh = vT + (size_t)h * 64 * NN;

  bf16x8 qf[4];
#pragma unroll
  for (int c = 0; c < 4; ++c)
    qf[c] = *(const bf16x8*)(qh + (size_t)(q0 + lq) * 64 + c * 16 + hi * 8);

  f32x16 o0 = {0}, o1 = {0};
  float m_r = -1e30f, l_r = 0.f;

  const int kend = ks * KCHUNK + KCHUNK;
  for (int k0 = ks * KCHUNK; k0 < kend; k0 += 32) {
    f32x16 s = {0};
#pragma unroll
    for (int c = 0; c < 4; ++c) {
      const bf16x8 kf = *(const bf16x8*)(kh + (size_t)(k0 + lq) * 64 + c * 16 + hi * 8);
      s = __builtin_amdgcn_mfma_f32_32x32x16_bf16(kf, qf[c], s, 0, 0, 0);
    }
    float mx = s[0];
#pragma unroll
    for (int i = 1; i < 16; ++i) mx = fmaxf(mx, s[i]);
    const float colmax = fmaxf(mx, __shfl_xor(mx, 32));
    if (!__all(colmax <= m_r + 8.f)) {          // defer-max (T13)
      const float m_new = fmaxf(m_r, colmax);
      const float corr = __expf(m_r - m_new);
#pragma unroll
      for (int i = 0; i < 16; ++i) { o0[i] *= corr; o1[i] *= corr; }
      l_r *= corr;
      m_r = m_new;
    }
    float p[16];
    float ssum = 0.f;
#pragma unroll
    for (int i = 0; i < 16; ++i) { p[i] = __expf(s[i] - m_r); ssum += p[i]; }
    l_r += ssum + __shfl_xor(ssum, 32);

    // pack P: word wi = keys (kk(2i,hi), kk(2i+1,hi)), kk(r,hi)=(r&3)+8*(r>>2)+4*hi
    unsigned wd[8];
#pragma unroll
    for (int i = 0; i < 8; ++i)
      wd[i] = (unsigned)f2bf(p[2 * i]) | ((unsigned)f2bf(p[2 * i + 1]) << 16);
    // redistribute to FLAT (pf elem j <-> key 8hi+j) matching flat-loaded V
    const unsigned t0 = __shfl_xor(hi ? wd[0] : wd[2], 32);
    const unsigned t1 = __shfl_xor(hi ? wd[1] : wd[3], 32);
    const unsigned t2 = __shfl_xor(hi ? wd[4] : wd[6], 32);
    const unsigned t3 = __shfl_xor(hi ? wd[5] : wd[7], 32);
    union { unsigned u[4]; bf16x8 b; } pf0, pf1;
    pf0.u[0] = hi ? t0 : wd[0];
    pf0.u[1] = hi ? t1 : wd[1];
    pf0.u[2] = hi ? wd[2] : t0;
    pf0.u[3] = hi ? wd[3] : t1;
    pf1.u[0] = hi ? t2 : wd[4];
    pf1.u[1] = hi ? t3 : wd[5];
    pf1.u[2] = hi ? wd[6] : t2;
    pf1.u[3] = hi ? wd[7] : t3;
    {
      const u16* vrow = vh + (size_t)lq * NN + k0 + hi * 8;
      const bf16x8 vf0 = *(const bf16x8*)(vrow);
      const bf16x8 vf1 = *(const bf16x8*)(vrow + 16);
      o0 = __builtin_amdgcn_mfma_f32_32x32x16_bf16(vf0, pf0.b, o0, 0, 0, 0);
      o0 = __builtin_amdgcn_mfma_f32_32x32x16_bf16(vf1, pf1.b, o0, 0, 0, 0);
    }
    {
      const u16* vrow = vh + (size_t)(32 + lq) * NN + k0 + hi * 8;
      const bf16x8 vf0 = *(const bf16x8*)(vrow);
      const bf16x8 vf1 = *(const bf16x8*)(vrow + 16);
      o1 = __builtin_amdgcn_mfma_f32_32x32x16_bf16(vf0, pf0.b, o1, 0, 0, 0);
      o1 = __builtin_amdgcn_mfma_f32_32x32x16_bf16(vf1, pf1.b, o1, 0, 0, 0);
    }
  }

  // epilogue: per-wave LDS transpose -> coalesced po rows [(h*NN+q)*(KSPLIT*64) + ks*64 + d]
  float* wld = sld[w];
  const size_t rowbase = (size_t)h * NN + q0;
  const int qq2 = (l >> 5), dd = l & 31;
#pragma unroll
  for (int r = 0; r < 16; ++r)
    wld[((r & 3) + 8 * (r >> 2) + 4 * hi) * 33 + lq] = o0[r];
#pragma unroll
  for (int qi = 0; qi < 16; ++qi) {
    const int qr = qi * 2 + qq2;
    po[(rowbase + qr) * (KSPLIT * 64) + ks * 64 + dd] = wld[dd * 33 + qr];
  }
#pragma unroll
  for (int r = 0; r < 16; ++r)
    wld[((r & 3) + 8 * (r >> 2) + 4 * hi) * 33 + lq] = o1[r];
#pragma unroll
  for (int qi = 0; qi < 16; ++qi) {
    const int qr = qi * 2 + qq2;
    po[(rowbase + qr) * (KSPLIT * 64) + ks * 64 + 32 + dd] = wld[dd * 33 + qr];
  }
  if (hi == 0) {
    const int pidx = (h * KSPLIT + ks) * NN + q0 + lq;
    pm[pidx] = m_r; pl[pidx] = l_r;
  }
}

// ---------------- combine split-K partials (contiguous reads) ----------------
__global__ __launch_bounds__(256) void combine2(
    const float* __restrict__ po, const float* __restrict__ pm,
    const float* __restrict__ pl, float* __restrict__ o)
{
  const int q = blockIdx.x;
  const int t = threadIdx.x;
  const int h = t >> 6, d = t & 63;
  float mloc[KSPLIT];
  float M = -1e30f;
#pragma unroll
  for (int i = 0; i < KSPLIT; ++i) {
    mloc[i] = pm[(h * KSPLIT + i) * NN + q];
    M = fmaxf(M, mloc[i]);
  }
  const size_t base = ((size_t)h * NN + q) * (KSPLIT * 64);
  float L = 0.f, acc = 0.f;
#pragma unroll
  for (int i = 0; i < KSPLIT; ++i) {
    const float wgt = __expf(mloc[i] - M);
    L += wgt * pl[(h * KSPLIT + i) * NN + q];
    acc += wgt * po[base + i * 64 + d];
  }
  o[(size_t)q * EMB + h * 64 + d] = acc / L;
}

// ---------------- launch ----------------
extern "C" void kernel_launch(void* const* d_in, const int* in_sizes, int n_in,
                              void* d_out, int out_size, void* d_ws, size_t ws_size,
                              hipStream_t stream)
{
  const float* tgt   = (const float*)d_in[0];
  const float* mem   = (const float*)d_in[1];
  const float* orig  = (const float*)d_in[2];
  const int*   eidx  = (const int*)d_in[3];
  const float* Wg    = (const float*)d_in[4];
  const float* att_s = (const float*)d_in[5];
  const float* att_d = (const float*)d_in[6];
  const float* bg    = (const float*)d_in[7];
  const float* ipw   = (const float*)d_in[8];
  const float* ipb   = (const float*)d_in[9];
  const float* opw   = (const float*)d_in[10];
  const float* opb   = (const float*)d_in[11];
  const float* l1w   = (const float*)d_in[12];
  const float* l1b   = (const float*)d_in[13];
  float* out = (float*)d_out;

  char* ws = (char*)d_ws;
  size_t off = 0;
  auto alloc = [&](size_t bytes) -> void* {
    void* p = ws + off;
    off += (bytes + 255) & ~((size_t)255);
    return p;
  };
  float* xh    = (float*)alloc((size_t)NN * EMB * 4);   // also reused as obuf (after gat_gather)
  float* tbuf  = (float*)alloc((size_t)NN * EMB * 4);   // also reused as fused (after qkv_mfma)
  float* a_s   = (float*)alloc((size_t)NN * HH * 4);
  float* a_d   = (float*)alloc((size_t)NN * HH * 4);
  int* counts  = (int*)alloc((size_t)NN * 4);
  int* offs    = (int*)alloc((size_t)NN * 4);
  int* ssrc    = (int*)alloc((size_t)ET * 4);
  u16* qb      = (u16*)alloc((size_t)NN * EMB * 2);
  u16* kbuf    = (u16*)alloc((size_t)NN * EMB * 2);
  u16* vT      = (u16*)alloc((size_t)NN * EMB * 2);
  float* po    = (float*)alloc((size_t)HH * NN * KSPLIT * 64 * 4);
  float* pm    = (float*)alloc((size_t)HH * KSPLIT * NN * 4);
  float* pl    = (float*)alloc((size_t)HH * KSPLIT * NN * 4);
  float* obuf  = xh;     // safe: combine2 runs after gat_gather's last xh read
  float* fused = tbuf;   // safe: out_proj runs after qkv_mfma's last tbuf read

  (void)hipMemsetAsync(counts, 0, (size_t)NN * 4, stream);

  mgemm_nt<<<dim3(EMB / 64, NN / 64), 256, 0, stream>>>(tgt, Wg, xh, NN, EMB, FIN);
  att_sums<<<NN, 256, 0, stream>>>(xh, att_s, att_d, a_s, a_d);
  edge_count<<<(ET + 255) / 256, 256, 0, stream>>>(eidx, counts);
  scan4096<<<1, 64, 0, stream>>>(counts, offs);
  edge_scatter<<<(ET + 255) / 256, 256, 0, stream>>>(eidx, offs, ssrc);
  gat_gather<<<NN, 256, 0, stream>>>(xh, a_s, a_d, offs, counts, ssrc, bg, tbuf);

  qkv_mfma<<<dim3(EMB / 64, NN / 64, 3), 256, 0, stream>>>(
      tbuf, mem, orig, ipw, ipb, qb, kbuf, vT);

  flash32<<<dim3(32 * KSPLIT, HH), 256, 0, stream>>>(qb, kbuf, vT, po, pm, pl);
  combine2<<<NN, 256, 0, stream>>>(po, pm, pl, obuf);

  bgemm<<<dim3(EMB / 64, NN / 64), 256, 0, stream>>>(
      obuf, opw, opb, fused, NN, EMB, EMB, 0);
  bgemm<<<dim3(DFF / 64, NN / 64), 256, 0, stream>>>(
      fused, l1w, l1b, out, NN, DFF, EMB, 2);
}

// Round 18
// 208.514 us; speedup vs baseline: 1.1866x; 1.1866x over previous
//
#include <hip/hip_runtime.h>
#include <hip/hip_bf16.h>

#define NN   4096
#define EE   262144
#define ET   (EE + NN)
#define HH   4
#define EMB  256
#define DFF  128
#define FIN  128
#define KSPLIT 8
#define KCHUNK (NN / KSPLIT)

typedef float  f32x16  __attribute__((ext_vector_type(16)));
typedef __bf16 bf16x8  __attribute__((ext_vector_type(8)));
typedef unsigned short u16;
typedef unsigned short u16x4 __attribute__((ext_vector_type(4)));

__device__ __forceinline__ u16 f2bf(float f) {
  unsigned u = __float_as_uint(f);
  u += 0x7fffu + ((u >> 16) & 1u);   // RNE
  return (u16)(u >> 16);
}
// hi/lo bf16 split packed into one uint: lo16 = hi-part, hi16 = lo-part
__device__ __forceinline__ unsigned split1(float x) {
  const u16 h = f2bf(x);
  const float hf = __uint_as_float(((unsigned)h) << 16);
  const u16 l = f2bf(x - hf);
  return (unsigned)h | ((unsigned)l << 16);
}

// ------- split-precision MFMA GEMM, B in [K,Nn] layout (xh = tgt @ W_gat) -------
__global__ __launch_bounds__(256) void mgemm_nt(
    const float* __restrict__ A, const float* __restrict__ B,
    float* __restrict__ Cf, int M, int Nn, int K)
{
  __shared__ u16 Ah[64][40], Al[64][40], Bh[64][40], Bl[64][40];
  const int tid = threadIdx.x;
  const int m0 = blockIdx.y * 64, n0 = blockIdx.x * 64;
  const int w = tid >> 6, l = tid & 63, lq = l & 31, hi = l >> 5;
  const int wm = w >> 1, wn = w & 1;
  f32x16 acc = {0};
  for (int k0 = 0; k0 < K; k0 += 32) {
    __syncthreads();
#pragma unroll
    for (int it = 0; it < 2; ++it) {
      const int idx = tid + it * 256;
      {  // A[M,K]: row-major
        const int row = idx >> 3, slot = idx & 7;
        const float4 av = *(const float4*)(A + (size_t)(m0 + row) * K + k0 + slot * 4);
        const unsigned s0 = split1(av.x), s1 = split1(av.y), s2 = split1(av.z), s3 = split1(av.w);
        u16x4 hp = {(u16)s0, (u16)s1, (u16)s2, (u16)s3};
        u16x4 lp = {(u16)(s0 >> 16), (u16)(s1 >> 16), (u16)(s2 >> 16), (u16)(s3 >> 16)};
        *(u16x4*)(&Ah[row][slot * 4]) = hp;
        *(u16x4*)(&Al[row][slot * 4]) = lp;
      }
      {  // B[K,Nn]: stage transposed -> Bh[col][k]
        const int kr = idx >> 4, nq = idx & 15;
        const float4 bv = *(const float4*)(B + (size_t)(k0 + kr) * Nn + n0 + nq * 4);
        const unsigned s0 = split1(bv.x), s1 = split1(bv.y), s2 = split1(bv.z), s3 = split1(bv.w);
        Bh[nq * 4 + 0][kr] = (u16)s0; Bl[nq * 4 + 0][kr] = (u16)(s0 >> 16);
        Bh[nq * 4 + 1][kr] = (u16)s1; Bl[nq * 4 + 1][kr] = (u16)(s1 >> 16);
        Bh[nq * 4 + 2][kr] = (u16)s2; Bl[nq * 4 + 2][kr] = (u16)(s2 >> 16);
        Bh[nq * 4 + 3][kr] = (u16)s3; Bl[nq * 4 + 3][kr] = (u16)(s3 >> 16);
      }
    }
    __syncthreads();
#pragma unroll
    for (int c = 0; c < 2; ++c) {
      const bf16x8 ah = *(const bf16x8*)(&Ah[wm * 32 + lq][c * 16 + hi * 8]);
      const bf16x8 al = *(const bf16x8*)(&Al[wm * 32 + lq][c * 16 + hi * 8]);
      const bf16x8 bh = *(const bf16x8*)(&Bh[wn * 32 + lq][c * 16 + hi * 8]);
      const bf16x8 bl = *(const bf16x8*)(&Bl[wn * 32 + lq][c * 16 + hi * 8]);
      acc = __builtin_amdgcn_mfma_f32_32x32x16_bf16(ah, bh, acc, 0, 0, 0);
      acc = __builtin_amdgcn_mfma_f32_32x32x16_bf16(ah, bl, acc, 0, 0, 0);
      acc = __builtin_amdgcn_mfma_f32_32x32x16_bf16(al, bh, acc, 0, 0, 0);
    }
  }
  const int col = n0 + wn * 32 + lq;
#pragma unroll
  for (int r = 0; r < 16; ++r) {
    const int row = m0 + wm * 32 + (r & 3) + 8 * (r >> 2) + 4 * hi;
    Cf[(size_t)row * Nn + col] = acc[r];
  }
}

// ------- bf16 MFMA GEMM (out_proj, lin1): C = act(A[M,K] @ B[Nn,K]^T + bias) -------
__global__ __launch_bounds__(256) void bgemm(
    const float* __restrict__ A, const float* __restrict__ B, const float* __restrict__ bias,
    float* __restrict__ Cf, int M, int Nn, int K, int act)
{
  __shared__ u16 As[64][40], Bs[64][40];
  const int tid = threadIdx.x;
  const int m0 = blockIdx.y * 64, n0 = blockIdx.x * 64;
  const int w = tid >> 6, l = tid & 63, lq = l & 31, hi = l >> 5;
  const int wm = w >> 1, wn = w & 1;
  f32x16 acc = {0};
  for (int k0 = 0; k0 < K; k0 += 32) {
    __syncthreads();
#pragma unroll
    for (int it = 0; it < 2; ++it) {
      const int idx = tid + it * 256;
      const int row = idx >> 3, slot = idx & 7;
      const float4 av = *(const float4*)(A + (size_t)(m0 + row) * K + k0 + slot * 4);
      u16x4 ap = {f2bf(av.x), f2bf(av.y), f2bf(av.z), f2bf(av.w)};
      *(u16x4*)(&As[row][slot * 4]) = ap;
      const float4 bv = *(const float4*)(B + (size_t)(n0 + row) * K + k0 + slot * 4);
      u16x4 bp = {f2bf(bv.x), f2bf(bv.y), f2bf(bv.z), f2bf(bv.w)};
      *(u16x4*)(&Bs[row][slot * 4]) = bp;
    }
    __syncthreads();
#pragma unroll
    for (int c = 0; c < 2; ++c) {
      const bf16x8 af = *(const bf16x8*)(&As[wm * 32 + lq][c * 16 + hi * 8]);
      const bf16x8 bf = *(const bf16x8*)(&Bs[wn * 32 + lq][c * 16 + hi * 8]);
      acc = __builtin_amdgcn_mfma_f32_32x32x16_bf16(af, bf, acc, 0, 0, 0);
    }
  }
  const int col = n0 + wn * 32 + lq;
  const float bcol = bias ? bias[col] : 0.f;
#pragma unroll
  for (int r = 0; r < 16; ++r) {
    const int row = m0 + wm * 32 + (r & 3) + 8 * (r >> 2) + 4 * hi;
    float v = acc[r] + bcol;
    if (act == 2) v = fmaxf(v, 0.f);
    Cf[(size_t)row * Nn + col] = v;
  }
}

// ------- fused QKV projection: single bf16 MFMA (outputs bf16-rounded anyway) -------
__global__ __launch_bounds__(256) void qkv_mfma(
    const float* __restrict__ tbuf, const float* __restrict__ mem, const float* __restrict__ orig,
    const float* __restrict__ ipw, const float* __restrict__ ipb,
    u16* __restrict__ qb, u16* __restrict__ kbuf, u16* __restrict__ vT)
{
  __shared__ u16 As[64][40], Bs[64][40];
  const int z = blockIdx.z;
  const float* A = (z == 0) ? tbuf : (z == 1 ? mem : orig);
  const float* B = ipw + (size_t)z * EMB * EMB;
  const float* bias = ipb + z * EMB;
  const float oscale = (z == 0) ? 0.125f : 1.f;
  const int tid = threadIdx.x;
  const int m0 = blockIdx.y * 64, n0 = blockIdx.x * 64;
  const int w = tid >> 6, l = tid & 63, lq = l & 31, hi = l >> 5;
  const int wm = w >> 1, wn = w & 1;
  f32x16 acc = {0};
  for (int k0 = 0; k0 < EMB; k0 += 32) {
    __syncthreads();
#pragma unroll
    for (int it = 0; it < 2; ++it) {
      const int idx = tid + it * 256;
      const int row = idx >> 3, slot = idx & 7;
      const float4 av = *(const float4*)(A + (size_t)(m0 + row) * EMB + k0 + slot * 4);
      u16x4 ap = {f2bf(av.x), f2bf(av.y), f2bf(av.z), f2bf(av.w)};
      *(u16x4*)(&As[row][slot * 4]) = ap;
      const float4 bv = *(const float4*)(B + (size_t)(n0 + row) * EMB + k0 + slot * 4);
      u16x4 bp = {f2bf(bv.x), f2bf(bv.y), f2bf(bv.z), f2bf(bv.w)};
      *(u16x4*)(&Bs[row][slot * 4]) = bp;
    }
    __syncthreads();
#pragma unroll
    for (int c = 0; c < 2; ++c) {
      const bf16x8 af = *(const bf16x8*)(&As[wm * 32 + lq][c * 16 + hi * 8]);
      const bf16x8 bf = *(const bf16x8*)(&Bs[wn * 32 + lq][c * 16 + hi * 8]);
      acc = __builtin_amdgcn_mfma_f32_32x32x16_bf16(af, bf, acc, 0, 0, 0);
    }
  }
  const int col = n0 + wn * 32 + lq;
  const float bcol = bias[col];
  const int hh = col >> 6, dd = col & 63;
#pragma unroll
  for (int r = 0; r < 16; ++r) {
    const int row = m0 + wm * 32 + (r & 3) + 8 * (r >> 2) + 4 * hi;
    const u16 bw = f2bf((acc[r] + bcol) * oscale);
    if (z == 2) vT[((size_t)hh * 64 + dd) * NN + row] = bw;                  // V^T per head
    else if (z == 1) kbuf[((size_t)hh * NN + row) * 64 + dd] = bw;           // K row-major per head
    else qb[((size_t)hh * NN + row) * 64 + dd] = bw;                         // Q (pre-scaled 1/8)
  }
}

// ---------------- a_s / a_d per (node, head) ----------------
__global__ __launch_bounds__(256) void att_sums(const float* __restrict__ xh,
                                                const float* __restrict__ att_src,
                                                const float* __restrict__ att_dst,
                                                float* __restrict__ a_s, float* __restrict__ a_d)
{
  const int n = blockIdx.x, t = threadIdx.x;
  const int h = t >> 6, c = t & 63;
  const float v = xh[(size_t)n * EMB + t];
  float s1 = v * att_src[t];
  float s2 = v * att_dst[t];
#pragma unroll
  for (int off = 32; off >= 1; off >>= 1) {
    s1 += __shfl_down(s1, off);
    s2 += __shfl_down(s2, off);
  }
  if (c == 0) { a_s[n * HH + h] = s1; a_d[n * HH + h] = s2; }
}

// ---------------- counting sort of edges by destination ----------------
__global__ void edge_count(const int* __restrict__ ei, int* __restrict__ counts) {
  const int e = blockIdx.x * blockDim.x + threadIdx.x;
  if (e >= ET) return;
  const int dst = (e < EE) ? ei[EE + e] : (e - EE);
  atomicAdd(&counts[dst], 1);
}

__global__ __launch_bounds__(64) void scan4096(const int* __restrict__ counts, int* __restrict__ offs) {
  const int t = threadIdx.x;
  const int base = t * 64;
  int s = 0;
  for (int i = 0; i < 64; ++i) s += counts[base + i];
  int incl = s;
#pragma unroll
  for (int off = 1; off < 64; off <<= 1) {
    const int v = __shfl_up(incl, off);
    if (t >= off) incl += v;
  }
  int run = incl - s;
  for (int i = 0; i < 64; ++i) { offs[base + i] = run; run += counts[base + i]; }
}

// scatter bumps offs directly (no cursor buffer); offs[dst] ends at segment END.
__global__ void edge_scatter(const int* __restrict__ ei, int* __restrict__ offs,
                             int* __restrict__ ssrc) {
  const int e = blockIdx.x * blockDim.x + threadIdx.x;
  if (e >= ET) return;
  int src, dst;
  if (e < EE) { src = ei[e]; dst = ei[EE + e]; } else { src = dst = e - EE; }
  const int pos = atomicAdd(&offs[dst], 1);
  ssrc[pos] = src;
}

// ---------------- GAT gather: 4-way ILP unroll; beg = offs_end - deg ----------------
__global__ __launch_bounds__(256) void gat_gather(
    const float* __restrict__ xh, const float* __restrict__ a_s, const float* __restrict__ a_d,
    const int* __restrict__ offs, const int* __restrict__ counts, const int* __restrict__ ssrc,
    const float* __restrict__ b_gat, float* __restrict__ t_out)
{
  const int dst = blockIdx.x, tid = threadIdx.x;
  const int h = tid >> 6, c = tid & 63;
  const float ad = a_d[dst * HH + h];
  const int deg = counts[dst];
  const int beg = offs[dst] - deg;           // offs holds segment end after scatter
  float ac0 = 0.f, ac1 = 0.f, ac2 = 0.f, ac3 = 0.f;
  float dn0 = 0.f, dn1 = 0.f, dn2 = 0.f, dn3 = 0.f;
  int i = 0;
  for (; i + 4 <= deg; i += 4) {
    const int s0 = ssrc[beg + i];
    const int s1 = ssrc[beg + i + 1];
    const int s2 = ssrc[beg + i + 2];
    const int s3 = ssrc[beg + i + 3];
    const float A0 = a_s[s0 * HH + h];
    const float A1 = a_s[s1 * HH + h];
    const float A2 = a_s[s2 * HH + h];
    const float A3 = a_s[s3 * HH + h];
    const float x0 = xh[(size_t)s0 * EMB + h * 64 + c];
    const float x1 = xh[(size_t)s1 * EMB + h * 64 + c];
    const float x2 = xh[(size_t)s2 * EMB + h * 64 + c];
    const float x3 = xh[(size_t)s3 * EMB + h * 64 + c];
    float a0 = A0 + ad; a0 = a0 > 0.f ? a0 : 0.2f * a0;
    float a1 = A1 + ad; a1 = a1 > 0.f ? a1 : 0.2f * a1;
    float a2 = A2 + ad; a2 = a2 > 0.f ? a2 : 0.2f * a2;
    float a3 = A3 + ad; a3 = a3 > 0.f ? a3 : 0.2f * a3;
    const float p0 = __expf(a0);
    const float p1 = __expf(a1);
    const float p2 = __expf(a2);
    const float p3 = __expf(a3);
    dn0 += p0; ac0 += p0 * x0;
    dn1 += p1; ac1 += p1 * x1;
    dn2 += p2; ac2 += p2 * x2;
    dn3 += p3; ac3 += p3 * x3;
  }
  for (; i < deg; ++i) {
    const int src = ssrc[beg + i];
    float a = a_s[src * HH + h] + ad;
    a = a > 0.f ? a : 0.2f * a;
    const float p = __expf(a);
    dn0 += p;
    ac0 += p * xh[(size_t)src * EMB + h * 64 + c];
  }
  const float den = (dn0 + dn1) + (dn2 + dn3);
  const float accv = (ac0 + ac1) + (ac2 + ac3);
  float v = accv / (den + 1e-16f) + b_gat[tid];
  v = v > 0.f ? v : 0.01f * v;
  t_out[(size_t)dst * EMB + tid] = v;
}

// ---------------- flash attention: exact R11/R14/R15 body (VGPR=64, occ ~40%) — FROZEN ----------------
// po layout: po[(h*NN + q) * (KSPLIT*64) + i*64 + d]  -> combine2 reads contiguous.
__global__ __launch_bounds__(256) void flash32(
    const u16* __restrict__ qb, const u16* __restrict__ kb,
    const u16* __restrict__ vT, float* __restrict__ po,
    float* __restrict__ pm, float* __restrict__ pl)
{
  __shared__ float sld[4][32 * 33];            // per-wave transpose staging (17 KB)
  const int h = blockIdx.y;
  const int qgroup = blockIdx.x / KSPLIT, ks = blockIdx.x % KSPLIT;
  const int w = threadIdx.x >> 6, l = threadIdx.x & 63;
  const int lq = l & 31, hi = l >> 5;
  const int qtile = qgroup * 4 + w;            // 4 waves share the K/V stream (L1 reuse)
  const int q0 = qtile * 32;
  const u16* qh = qb + (size_t)h * NN * 64;
  const u16* kh = kb + (size_t)h * NN * 64;
  const u16* vh = vT + (size_t)h * 64 * NN;

  bf16x8 qf[4];
#pragma unroll
  for (int c = 0; c < 4; ++c)
    qf[c] = *(const bf16x8*)(qh + (size_t)(q0 + lq) * 64 + c * 16 + hi * 8);

  f32x16 o0 = {0}, o1 = {0};
  float m_r = -1e30f, l_r = 0.f;

  const int kend = ks * KCHUNK + KCHUNK;
  for (int k0 = ks * KCHUNK; k0 < kend; k0 += 32) {
    f32x16 s = {0};
#pragma unroll
    for (int c = 0; c < 4; ++c) {
      const bf16x8 kf = *(const bf16x8*)(kh + (size_t)(k0 + lq) * 64 + c * 16 + hi * 8);
      s = __builtin_amdgcn_mfma_f32_32x32x16_bf16(kf, qf[c], s, 0, 0, 0);
    }
    float mx = s[0];
#pragma unroll
    for (int i = 1; i < 16; ++i) mx = fmaxf(mx, s[i]);
    const float colmax = fmaxf(mx, __shfl_xor(mx, 32));
    if (!__all(colmax <= m_r + 8.f)) {          // defer-max (T13)
      const float m_new = fmaxf(m_r, colmax);
      const float corr = __expf(m_r - m_new);
#pragma unroll
      for (int i = 0; i < 16; ++i) { o0[i] *= corr; o1[i] *= corr; }
      l_r *= corr;
      m_r = m_new;
    }
    float p[16];
    float ssum = 0.f;
#pragma unroll
    for (int i = 0; i < 16; ++i) { p[i] = __expf(s[i] - m_r); ssum += p[i]; }
    l_r += ssum + __shfl_xor(ssum, 32);

    // pack P: word wi = keys (kk(2i,hi), kk(2i+1,hi)), kk(r,hi)=(r&3)+8*(r>>2)+4*hi
    unsigned wd[8];
#pragma unroll
    for (int i = 0; i < 8; ++i)
      wd[i] = (unsigned)f2bf(p[2 * i]) | ((unsigned)f2bf(p[2 * i + 1]) << 16);
    // redistribute to FLAT (pf elem j <-> key 8hi+j) matching flat-loaded V
    const unsigned t0 = __shfl_xor(hi ? wd[0] : wd[2], 32);
    const unsigned t1 = __shfl_xor(hi ? wd[1] : wd[3], 32);
    const unsigned t2 = __shfl_xor(hi ? wd[4] : wd[6], 32);
    const unsigned t3 = __shfl_xor(hi ? wd[5] : wd[7], 32);
    union { unsigned u[4]; bf16x8 b; } pf0, pf1;
    pf0.u[0] = hi ? t0 : wd[0];
    pf0.u[1] = hi ? t1 : wd[1];
    pf0.u[2] = hi ? wd[2] : t0;
    pf0.u[3] = hi ? wd[3] : t1;
    pf1.u[0] = hi ? t2 : wd[4];
    pf1.u[1] = hi ? t3 : wd[5];
    pf1.u[2] = hi ? wd[6] : t2;
    pf1.u[3] = hi ? wd[7] : t3;
    {
      const u16* vrow = vh + (size_t)lq * NN + k0 + hi * 8;
      const bf16x8 vf0 = *(const bf16x8*)(vrow);
      const bf16x8 vf1 = *(const bf16x8*)(vrow + 16);
      o0 = __builtin_amdgcn_mfma_f32_32x32x16_bf16(vf0, pf0.b, o0, 0, 0, 0);
      o0 = __builtin_amdgcn_mfma_f32_32x32x16_bf16(vf1, pf1.b, o0, 0, 0, 0);
    }
    {
      const u16* vrow = vh + (size_t)(32 + lq) * NN + k0 + hi * 8;
      const bf16x8 vf0 = *(const bf16x8*)(vrow);
      const bf16x8 vf1 = *(const bf16x8*)(vrow + 16);
      o1 = __builtin_amdgcn_mfma_f32_32x32x16_bf16(vf0, pf0.b, o1, 0, 0, 0);
      o1 = __builtin_amdgcn_mfma_f32_32x32x16_bf16(vf1, pf1.b, o1, 0, 0, 0);
    }
  }

  // epilogue: per-wave LDS transpose -> coalesced po rows [(h*NN+q)*(KSPLIT*64) + ks*64 + d]
  float* wld = sld[w];
  const size_t rowbase = (size_t)h * NN + q0;
  const int qq2 = (l >> 5), dd = l & 31;
#pragma unroll
  for (int r = 0; r < 16; ++r)
    wld[((r & 3) + 8 * (r >> 2) + 4 * hi) * 33 + lq] = o0[r];
#pragma unroll
  for (int qi = 0; qi < 16; ++qi) {
    const int qr = qi * 2 + qq2;
    po[(rowbase + qr) * (KSPLIT * 64) + ks * 64 + dd] = wld[dd * 33 + qr];
  }
#pragma unroll
  for (int r = 0; r < 16; ++r)
    wld[((r & 3) + 8 * (r >> 2) + 4 * hi) * 33 + lq] = o1[r];
#pragma unroll
  for (int qi = 0; qi < 16; ++qi) {
    const int qr = qi * 2 + qq2;
    po[(rowbase + qr) * (KSPLIT * 64) + ks * 64 + 32 + dd] = wld[dd * 33 + qr];
  }
  if (hi == 0) {
    const int pidx = (h * KSPLIT + ks) * NN + q0 + lq;
    pm[pidx] = m_r; pl[pidx] = l_r;
  }
}

// ---------------- combine split-K partials (contiguous reads) ----------------
__global__ __launch_bounds__(256) void combine2(
    const float* __restrict__ po, const float* __restrict__ pm,
    const float* __restrict__ pl, float* __restrict__ o)
{
  const int q = blockIdx.x;
  const int t = threadIdx.x;
  const int h = t >> 6, d = t & 63;
  float mloc[KSPLIT];
  float M = -1e30f;
#pragma unroll
  for (int i = 0; i < KSPLIT; ++i) {
    mloc[i] = pm[(h * KSPLIT + i) * NN + q];
    M = fmaxf(M, mloc[i]);
  }
  const size_t base = ((size_t)h * NN + q) * (KSPLIT * 64);
  float L = 0.f, acc = 0.f;
#pragma unroll
  for (int i = 0; i < KSPLIT; ++i) {
    const float wgt = __expf(mloc[i] - M);
    L += wgt * pl[(h * KSPLIT + i) * NN + q];
    acc += wgt * po[base + i * 64 + d];
  }
  o[(size_t)q * EMB + h * 64 + d] = acc / L;
}

// ---------------- launch ----------------
extern "C" void kernel_launch(void* const* d_in, const int* in_sizes, int n_in,
                              void* d_out, int out_size, void* d_ws, size_t ws_size,
                              hipStream_t stream)
{
  const float* tgt   = (const float*)d_in[0];
  const float* mem   = (const float*)d_in[1];
  const float* orig  = (const float*)d_in[2];
  const int*   eidx  = (const int*)d_in[3];
  const float* Wg    = (const float*)d_in[4];
  const float* att_s = (const float*)d_in[5];
  const float* att_d = (const float*)d_in[6];
  const float* bg    = (const float*)d_in[7];
  const float* ipw   = (const float*)d_in[8];
  const float* ipb   = (const float*)d_in[9];
  const float* opw   = (const float*)d_in[10];
  const float* opb   = (const float*)d_in[11];
  const float* l1w   = (const float*)d_in[12];
  const float* l1b   = (const float*)d_in[13];
  float* out = (float*)d_out;

  char* ws = (char*)d_ws;
  size_t off = 0;
  auto alloc = [&](size_t bytes) -> void* {
    void* p = ws + off;
    off += (bytes + 255) & ~((size_t)255);
    return p;
  };
  float* xh    = (float*)alloc((size_t)NN * EMB * 4);   // also reused as obuf (after gat_gather)
  float* tbuf  = (float*)alloc((size_t)NN * EMB * 4);   // also reused as fused (after qkv_mfma)
  float* a_s   = (float*)alloc((size_t)NN * HH * 4);
  float* a_d   = (float*)alloc((size_t)NN * HH * 4);
  int* counts  = (int*)alloc((size_t)NN * 4);
  int* offs    = (int*)alloc((size_t)NN * 4);
  int* ssrc    = (int*)alloc((size_t)ET * 4);
  u16* qb      = (u16*)alloc((size_t)NN * EMB * 2);
  u16* kbuf    = (u16*)alloc((size_t)NN * EMB * 2);
  u16* vT      = (u16*)alloc((size_t)NN * EMB * 2);
  float* po    = (float*)alloc((size_t)HH * NN * KSPLIT * 64 * 4);
  float* pm    = (float*)alloc((size_t)HH * KSPLIT * NN * 4);
  float* pl    = (float*)alloc((size_t)HH * KSPLIT * NN * 4);
  float* obuf  = xh;     // safe: combine2 runs after gat_gather's last xh read
  float* fused = tbuf;   // safe: out_proj runs after qkv_mfma's last tbuf read

  (void)hipMemsetAsync(counts, 0, (size_t)NN * 4, stream);

  mgemm_nt<<<dim3(EMB / 64, NN / 64), 256, 0, stream>>>(tgt, Wg, xh, NN, EMB, FIN);
  att_sums<<<NN, 256, 0, stream>>>(xh, att_s, att_d, a_s, a_d);
  edge_count<<<(ET + 255) / 256, 256, 0, stream>>>(eidx, counts);
  scan4096<<<1, 64, 0, stream>>>(counts, offs);
  edge_scatter<<<(ET + 255) / 256, 256, 0, stream>>>(eidx, offs, ssrc);
  gat_gather<<<NN, 256, 0, stream>>>(xh, a_s, a_d, offs, counts, ssrc, bg, tbuf);

  qkv_mfma<<<dim3(EMB / 64, NN / 64, 3), 256, 0, stream>>>(
      tbuf, mem, orig, ipw, ipb, qb, kbuf, vT);

  flash32<<<dim3(32 * KSPLIT, HH), 256, 0, stream>>>(qb, kbuf, vT, po, pm, pl);
  combine2<<<NN, 256, 0, stream>>>(po, pm, pl, obuf);

  bgemm<<<dim3(EMB / 64, NN / 64), 256, 0, stream>>>(
      obuf, opw, opb, fused, NN, EMB, EMB, 0);
  bgemm<<<dim3(DFF / 64, NN / 64), 256, 0, stream>>>(
      fused, l1w, l1b, out, NN, DFF, EMB, 2);
}